// Round 1
// baseline (449.773 us; speedup 1.0000x reference)
//
#include <hip/hip_runtime.h>
#include <math.h>

#define LL 2048
#define BB 128
#define HH 300
#define HV4 75   // HH / 4

// Kernel 1: v_t[b][h] = sum_k W[k][h] * hidden[k][b]
// (W^T @ hidden, stored transposed so each b's 300-vector is contiguous)
// Tiny: 38400 outputs x 300 MACs. W reads coalesced (consecutive h per thread),
// hidden reads broadcast. All L2-resident after first touch.
__global__ void __launch_bounds__(256) compute_v(const float* __restrict__ W,
                                                 const float* __restrict__ hidden,
                                                 float* __restrict__ v_t) {
    int t = blockIdx.x * blockDim.x + threadIdx.x;
    if (t >= BB * HH) return;
    int b = t / HH;
    int h = t - b * HH;
    float s = 0.f;
#pragma unroll 4
    for (int k = 0; k < HH; ++k)
        s = fmaf(W[k * HH + h], hidden[k * BB + b], s);
    v_t[b * HH + h] = s;
}

// Kernel 2 (the 315 MB stream): one wave per (l,b) row.
// energies[l*BB + b] = dot(qv[l,b,:], v_t[b,:])   -- 75 float4 per row.
// Bias term omitted: it adds a per-b constant along the softmax axis -> no-op.
__global__ void __launch_bounds__(256) compute_energies(
        const float4* __restrict__ qv4,
        const float4* __restrict__ v4,
        float* __restrict__ energies) {
    int wave = threadIdx.x >> 6;
    int lane = threadIdx.x & 63;
    int row  = blockIdx.x * 4 + wave;          // row = l*BB + b, in [0, LL*BB)
    int b    = row & (BB - 1);

    const float4* q = qv4 + (size_t)row * HV4;
    const float4* v = v4  + (size_t)b   * HV4;

    float4 a0 = q[lane];
    float4 b0 = v[lane];
    float s = a0.x * b0.x + a0.y * b0.y + a0.z * b0.z + a0.w * b0.w;
    if (lane < HV4 - 64) {                     // lanes 0..10 cover elements 64..74
        float4 a1 = q[64 + lane];
        float4 b1 = v[64 + lane];
        s += a1.x * b1.x + a1.y * b1.y + a1.z * b1.z + a1.w * b1.w;
    }
#pragma unroll
    for (int off = 32; off > 0; off >>= 1)
        s += __shfl_down(s, off, 64);
    if (lane == 0)
        energies[row] = s;                     // [L][B] layout: 4 adjacent dwords/block
}

// Kernel 3: softmax over l for each b. One block per b.
// energies layout [L][B] -> element l is at energies[l*BB + b].
// Output attn[0,b,l] -> out[b*LL + l].
__global__ void __launch_bounds__(256) softmax_rows(
        const float* __restrict__ energies,
        float* __restrict__ out) {
    int b    = blockIdx.x;
    int tid  = threadIdx.x;
    int lane = tid & 63;
    int wave = tid >> 6;

    __shared__ float redm[4];
    __shared__ float reds[4];

    float vals[8];
    float m = -INFINITY;
#pragma unroll
    for (int i = 0; i < 8; ++i) {
        int l = tid + i * 256;
        vals[i] = energies[l * BB + b];
        m = fmaxf(m, vals[i]);
    }
#pragma unroll
    for (int off = 32; off > 0; off >>= 1)
        m = fmaxf(m, __shfl_down(m, off, 64));
    if (lane == 0) redm[wave] = m;
    __syncthreads();
    m = fmaxf(fmaxf(redm[0], redm[1]), fmaxf(redm[2], redm[3]));

    float s = 0.f;
#pragma unroll
    for (int i = 0; i < 8; ++i) {
        vals[i] = __expf(vals[i] - m);
        s += vals[i];
    }
#pragma unroll
    for (int off = 32; off > 0; off >>= 1)
        s += __shfl_down(s, off, 64);
    if (lane == 0) reds[wave] = s;
    __syncthreads();
    s = reds[0] + reds[1] + reds[2] + reds[3];
    float inv = 1.f / s;

#pragma unroll
    for (int i = 0; i < 8; ++i)
        out[b * LL + tid + i * 256] = vals[i] * inv;
}

extern "C" void kernel_launch(void* const* d_in, const int* in_sizes, int n_in,
                              void* d_out, int out_size, void* d_ws, size_t ws_size,
                              hipStream_t stream) {
    const float* hidden = (const float*)d_in[0];   // [H, B]
    const float* qv     = (const float*)d_in[1];   // [L, B, H]
    const float* W      = (const float*)d_in[2];   // [H, H]
    // d_in[3] = bias[H]: softmax-shift-invariant, intentionally unused.
    float* out = (float*)d_out;                    // [B, L] (leading 1 squeezed)

    float* v_t      = (float*)d_ws;                // BB*HH floats = 153600 B (16B-aligned rows)
    float* energies = v_t + BB * HH;               // LL*BB floats = 1 MB

    compute_v<<<(BB * HH + 255) / 256, 256, 0, stream>>>(W, hidden, v_t);
    compute_energies<<<(LL * BB) / 4, 256, 0, stream>>>(
        (const float4*)qv, (const float4*)v_t, energies);
    softmax_rows<<<BB, 256, 0, stream>>>(energies, out);
}